// Round 1
// baseline (5991.068 us; speedup 1.0000x reference)
//
#include <hip/hip_runtime.h>
#include <math.h>

typedef __bf16 bf16;
typedef __bf16 bf16x4 __attribute__((ext_vector_type(4)));
typedef __bf16 bf16x8 __attribute__((ext_vector_type(8)));
typedef float f32x16 __attribute__((ext_vector_type(16)));

constexpr int D_HID = 2048;   // hidden size
constexpr int T_TOK = 1024;   // tokens
constexpr int NEXP  = 64;     // routed experts
constexpr int TOPK  = 6;
constexpr int I_RT  = 1408;   // routed intermediate
constexpr int I_SH  = 2816;   // shared intermediate (SHI)
constexpr float RSFV = 2.5f;

// ---------------------------------------------------------------------------
// Kernel 1: router logits + grouped top-k (fp32, exact semantics)
// ---------------------------------------------------------------------------
__global__ __launch_bounds__(256) void router_topk_kernel(
    const float* __restrict__ X, const float* __restrict__ GW,
    const float* __restrict__ bias, int* __restrict__ topk_ids,
    float* __restrict__ topk_w) {
  int t = blockIdx.x;
  int tid = threadIdx.x;
  int e = tid >> 2, q = tid & 3;
  const float4* xv = (const float4*)(X + (size_t)t * D_HID + q * 512);
  const float4* gv = (const float4*)(GW + (size_t)e * D_HID + q * 512);
  float s = 0.f;
#pragma unroll 8
  for (int i = 0; i < 128; ++i) {
    float4 a = xv[i], b = gv[i];
    s += a.x * b.x + a.y * b.y + a.z * b.z + a.w * b.w;
  }
  s += __shfl_xor(s, 1);
  s += __shfl_xor(s, 2);
  __shared__ float sc_s[64];  // sigmoid scores (un-biased)
  __shared__ float sf_s[64];  // scores + bias (for selection)
  if (q == 0) {
    float sg = 1.f / (1.f + expf(-s));
    sc_s[e] = sg;
    sf_s[e] = sg + bias[e];
  }
  __syncthreads();
  if (tid != 0) return;
  // --- serial grouped top-k (matches jax.lax.top_k tie-breaking: lowest idx) ---
  float gs[8];
#pragma unroll
  for (int g = 0; g < 8; ++g) {
    float m1 = -INFINITY, m2 = -INFINITY;
    for (int j = 0; j < 8; ++j) {
      float v = sf_s[g * 8 + j];
      if (v > m1) { m2 = m1; m1 = v; }
      else if (v > m2) { m2 = v; }
    }
    gs[g] = m1 + m2;
  }
  unsigned gsel = 0;
  for (int j = 0; j < 3; ++j) {
    int bi = 0; float bv = -INFINITY;
#pragma unroll
    for (int g = 0; g < 8; ++g) {
      bool sel = (gsel >> g) & 1u;
      if (!sel && gs[g] > bv) { bv = gs[g]; bi = g; }
    }
    gsel |= 1u << bi;
  }
  for (int i = 0; i < 64; ++i)
    if (!((gsel >> (i >> 3)) & 1u)) sf_s[i] = -INFINITY;
  float wsum = 0.f;
  int ids[6]; float ws[6];
  for (int j = 0; j < 6; ++j) {
    int bi = 0; float bv = -INFINITY;
    for (int i = 0; i < 64; ++i) {
      float v = sf_s[i];
      if (v > bv) { bv = v; bi = i; }
    }
    sf_s[bi] = -INFINITY;
    ids[j] = bi;
    float wv = sc_s[bi];
    ws[j] = wv; wsum += wv;
  }
  float inv = 1.f / (wsum + 1e-20f);
#pragma unroll
  for (int j = 0; j < 6; ++j) {
    topk_ids[t * TOPK + j] = ids[j];
    topk_w[t * TOPK + j] = ws[j] * inv;
  }
}

// ---------------------------------------------------------------------------
// Kernel 2: count + exclusive scan + scatter pairs into per-expert segments
// (single block so no global sync needed)
// ---------------------------------------------------------------------------
__global__ __launch_bounds__(1024) void scatter_kernel(
    const int* __restrict__ topk_ids, const float* __restrict__ topk_w,
    int* __restrict__ offsets, int* __restrict__ tok_list,
    float* __restrict__ pair_w) {
  __shared__ int cnt[64], off_s[65], cur[64];
  int tid = threadIdx.x;
  if (tid < 64) { cnt[tid] = 0; cur[tid] = 0; }
  __syncthreads();
  for (int p = tid; p < T_TOK * TOPK; p += 1024)
    atomicAdd(&cnt[topk_ids[p]], 1);
  __syncthreads();
  if (tid == 0) {
    int acc = 0;
    for (int e2 = 0; e2 < 64; ++e2) { off_s[e2] = acc; acc += cnt[e2]; }
    off_s[64] = acc;
  }
  __syncthreads();
  if (tid < 65) offsets[tid] = off_s[tid];
  for (int p = tid; p < T_TOK * TOPK; p += 1024) {
    int e2 = topk_ids[p];
    int pos = atomicAdd(&cur[e2], 1);
    int idx = off_s[e2] + pos;
    tok_list[idx] = p / TOPK;
    pair_w[idx] = topk_w[p];
  }
}

// ---------------------------------------------------------------------------
// GEMM1: h = silu(X @ Wgate.T) * (X @ Wup.T), output bf16
// fp32 inputs converted to bf16 while staging to LDS; 32x32x16 bf16 MFMA.
// W13 layout: [E][2*Idim][D]  (gate rows 0..Idim-1, up rows Idim..2Idim-1)
// ---------------------------------------------------------------------------
template <int BM, int BNH, int BK>
__global__ __launch_bounds__(256) void gemm1_kernel(
    const float* __restrict__ X, const float* __restrict__ W13,
    bf16* __restrict__ H, const int* __restrict__ tok_list,
    const int* __restrict__ offsets, int nrows_fixed, int Idim) {
  static_assert(BM == 128 && BNH == 64 && BK == 64, "tile fixed");
  int eid = blockIdx.z;
  int seg0 = offsets ? offsets[eid] : 0;
  int seg1 = offsets ? offsets[eid + 1] : nrows_fixed;
  int n = seg1 - seg0;
  int m0 = blockIdx.x * BM;
  if (m0 >= n) return;
  int c0 = blockIdx.y * BNH;
  const float* W13e = W13 + (size_t)eid * (2 * (size_t)Idim) * D_HID;

  __shared__ __align__(16) char smem[(BM * BK + 2 * BNH * BK) * 2];
  char* smA = smem;                    // [128][64] bf16, row stride 128B, xor-swizzled
  char* smB = smem + BM * BK * 2;      // [128][64] bf16 (64 gate rows + 64 up rows)
  int tid = threadIdx.x;

  // staging descriptors: A = 2048 float4-chunks, B = 2048 float4-chunks, 8 each
  const float* aptr[8]; int aoff[8]; bool aval[8];
#pragma unroll
  for (int j = 0; j < 8; ++j) {
    int c = tid + j * 256;
    int row = c >> 4, kc = (c & 15) << 2;
    aoff[j] = (row << 7) + (((kc << 1)) ^ ((row & 7) << 4));
    int gr = m0 + row;
    aval[j] = gr < n;
    int tok = aval[j] ? (tok_list ? tok_list[seg0 + gr] : gr) : 0;
    aptr[j] = X + (size_t)tok * D_HID + kc;
  }
  const float* bptr[8]; int boff[8];
#pragma unroll
  for (int j = 0; j < 8; ++j) {
    int c = tid + j * 256;
    int row = c >> 4, kc = (c & 15) << 2;
    boff[j] = (row << 7) + (((kc << 1)) ^ ((row & 7) << 4));
    int wrow = (row < BNH) ? (c0 + row) : (Idim + c0 + (row - BNH));
    bptr[j] = W13e + (size_t)wrow * D_HID + kc;
  }

  int lane = tid & 63, wv = tid >> 6;
  int wm = wv >> 1, wn = wv & 1;
  int lr = lane & 31, lk = (lane >> 5) << 3;
  int ar0 = wm * 64 + lr, ar1 = ar0 + 32;
  int br0 = wn * 32 + lr, br1 = br0 + 64;  // gate row, up row in smB

  f32x16 accg[2] = {}, accu[2] = {};

  for (int ks = 0; ks < D_HID / BK; ++ks) {
#pragma unroll
    for (int j = 0; j < 8; ++j) {
      float4 v = make_float4(0.f, 0.f, 0.f, 0.f);
      if (aval[j]) v = *(const float4*)(aptr[j]);
      bf16x4 hv = {(bf16)v.x, (bf16)v.y, (bf16)v.z, (bf16)v.w};
      *(bf16x4*)(smA + aoff[j]) = hv;
      aptr[j] += BK;
    }
#pragma unroll
    for (int j = 0; j < 8; ++j) {
      float4 v = *(const float4*)(bptr[j]);
      bf16x4 hv = {(bf16)v.x, (bf16)v.y, (bf16)v.z, (bf16)v.w};
      *(bf16x4*)(smB + boff[j]) = hv;
      bptr[j] += BK;
    }
    __syncthreads();
#pragma unroll
    for (int kk = 0; kk < BK / 16; ++kk) {
      int k2 = (kk * 16 + lk) << 1;
      bf16x8 a0 = *(const bf16x8*)(smA + (ar0 << 7) + (k2 ^ ((ar0 & 7) << 4)));
      bf16x8 a1 = *(const bf16x8*)(smA + (ar1 << 7) + (k2 ^ ((ar1 & 7) << 4)));
      bf16x8 bg = *(const bf16x8*)(smB + (br0 << 7) + (k2 ^ ((br0 & 7) << 4)));
      bf16x8 bu = *(const bf16x8*)(smB + (br1 << 7) + (k2 ^ ((br1 & 7) << 4)));
      accg[0] = __builtin_amdgcn_mfma_f32_32x32x16_bf16(a0, bg, accg[0], 0, 0, 0);
      accg[1] = __builtin_amdgcn_mfma_f32_32x32x16_bf16(a1, bg, accg[1], 0, 0, 0);
      accu[0] = __builtin_amdgcn_mfma_f32_32x32x16_bf16(a0, bu, accu[0], 0, 0, 0);
      accu[1] = __builtin_amdgcn_mfma_f32_32x32x16_bf16(a1, bu, accu[1], 0, 0, 0);
    }
    __syncthreads();
  }

  // epilogue: silu(gate)*up, store bf16. C layout: col=lane&31,
  // row=(reg&3)+8*(reg>>2)+4*(lane>>5)
  int gcol = c0 + wn * 32 + lr;
#pragma unroll
  for (int mf = 0; mf < 2; ++mf) {
    int rowb = wm * 64 + mf * 32 + ((lane >> 5) << 2);
#pragma unroll
    for (int r = 0; r < 16; ++r) {
      int rl = rowb + (r & 3) + ((r >> 2) << 3);
      if (m0 + rl < n) {
        float g = accg[mf][r], u = accu[mf][r];
        float hv = g / (1.f + __expf(-g)) * u;
        H[(size_t)(seg0 + m0 + rl) * Idim + gcol] = (bf16)hv;
      }
    }
  }
}

// ---------------------------------------------------------------------------
// GEMM2: y = h @ W2.T ; ATOMIC: Out[tok] += RSF*w*y (routed)
//                       else:   Out[row]  = y        (shared, initializes Out)
// W2 layout: [E][D][Kdim]
// ---------------------------------------------------------------------------
template <int BM, int BN, int BK, bool ATOMIC>
__global__ __launch_bounds__(256) void gemm2_kernel(
    const bf16* __restrict__ Hin, const float* __restrict__ W2,
    float* __restrict__ Out, const int* __restrict__ tok_list,
    const int* __restrict__ offsets, const float* __restrict__ pair_w,
    int nrows_fixed, int Kdim) {
  static_assert(BM == 128 && BN == 128 && BK == 64, "tile fixed");
  int eid = blockIdx.z;
  int seg0 = offsets ? offsets[eid] : 0;
  int seg1 = offsets ? offsets[eid + 1] : nrows_fixed;
  int n = seg1 - seg0;
  int m0 = blockIdx.x * BM;
  if (m0 >= n) return;
  int c0 = blockIdx.y * BN;
  const float* W2e = W2 + (size_t)eid * D_HID * (size_t)Kdim;

  __shared__ __align__(16) char smem[(BM * BK + BN * BK) * 2];
  char* smA = smem;
  char* smB = smem + BM * BK * 2;
  int tid = threadIdx.x;

  // A (bf16 source): 1024 16B-chunks, 4/thread
  const bf16* aptr[4]; int aoff[4]; bool aval[4];
#pragma unroll
  for (int j = 0; j < 4; ++j) {
    int c = tid + j * 256;
    int row = c >> 3, kc = (c & 7) << 3;
    aoff[j] = (row << 7) + (((kc << 1)) ^ ((row & 7) << 4));
    int gr = m0 + row;
    aval[j] = gr < n;
    aptr[j] = Hin + (size_t)(seg0 + (aval[j] ? gr : 0)) * Kdim + kc;
  }
  // B (fp32 source): 2048 float4-chunks, 8/thread
  const float* bptr[8]; int boff[8];
#pragma unroll
  for (int j = 0; j < 8; ++j) {
    int c = tid + j * 256;
    int row = c >> 4, kc = (c & 15) << 2;
    boff[j] = (row << 7) + (((kc << 1)) ^ ((row & 7) << 4));
    bptr[j] = W2e + (size_t)(c0 + row) * Kdim + kc;
  }

  int lane = tid & 63, wv = tid >> 6;
  int wm = wv >> 1, wn = wv & 1;
  int lr = lane & 31, lk = (lane >> 5) << 3;
  int ar0 = wm * 64 + lr, ar1 = ar0 + 32;
  int bc0 = wn * 64 + lr, bc1 = bc0 + 32;

  f32x16 acc[2][2] = {};

  int ksteps = Kdim >> 6;
  for (int ks = 0; ks < ksteps; ++ks) {
#pragma unroll
    for (int j = 0; j < 4; ++j) {
      uint4 v = make_uint4(0u, 0u, 0u, 0u);
      if (aval[j]) v = *(const uint4*)(aptr[j]);
      *(uint4*)(smA + aoff[j]) = v;
      aptr[j] += BK;
    }
#pragma unroll
    for (int j = 0; j < 8; ++j) {
      float4 v = *(const float4*)(bptr[j]);
      bf16x4 hv = {(bf16)v.x, (bf16)v.y, (bf16)v.z, (bf16)v.w};
      *(bf16x4*)(smB + boff[j]) = hv;
      bptr[j] += BK;
    }
    __syncthreads();
#pragma unroll
    for (int kk = 0; kk < BK / 16; ++kk) {
      int k2 = (kk * 16 + lk) << 1;
      bf16x8 a0 = *(const bf16x8*)(smA + (ar0 << 7) + (k2 ^ ((ar0 & 7) << 4)));
      bf16x8 a1 = *(const bf16x8*)(smA + (ar1 << 7) + (k2 ^ ((ar1 & 7) << 4)));
      bf16x8 b0 = *(const bf16x8*)(smB + (bc0 << 7) + (k2 ^ ((bc0 & 7) << 4)));
      bf16x8 b1 = *(const bf16x8*)(smB + (bc1 << 7) + (k2 ^ ((bc1 & 7) << 4)));
      acc[0][0] = __builtin_amdgcn_mfma_f32_32x32x16_bf16(a0, b0, acc[0][0], 0, 0, 0);
      acc[0][1] = __builtin_amdgcn_mfma_f32_32x32x16_bf16(a0, b1, acc[0][1], 0, 0, 0);
      acc[1][0] = __builtin_amdgcn_mfma_f32_32x32x16_bf16(a1, b0, acc[1][0], 0, 0, 0);
      acc[1][1] = __builtin_amdgcn_mfma_f32_32x32x16_bf16(a1, b1, acc[1][1], 0, 0, 0);
    }
    __syncthreads();
  }

#pragma unroll
  for (int mf = 0; mf < 2; ++mf) {
    int rowb = wm * 64 + mf * 32 + ((lane >> 5) << 2);
#pragma unroll
    for (int r = 0; r < 16; ++r) {
      int rl = rowb + (r & 3) + ((r >> 2) << 3);
      if (m0 + rl >= n) continue;
      if (ATOMIC) {
        int t = tok_list[seg0 + m0 + rl];
        float w = pair_w[seg0 + m0 + rl] * RSFV;
#pragma unroll
        for (int nf = 0; nf < 2; ++nf) {
          int col = c0 + wn * 64 + nf * 32 + lr;
          atomicAdd(Out + (size_t)t * D_HID + col, w * acc[mf][nf][r]);
        }
      } else {
#pragma unroll
        for (int nf = 0; nf < 2; ++nf) {
          int col = c0 + wn * 64 + nf * 32 + lr;
          Out[(size_t)(m0 + rl) * D_HID + col] = acc[mf][nf][r];
        }
      }
    }
  }
}

// ---------------------------------------------------------------------------
extern "C" void kernel_launch(void* const* d_in, const int* in_sizes, int n_in,
                              void* d_out, int out_size, void* d_ws, size_t ws_size,
                              hipStream_t stream) {
  const float* X    = (const float*)d_in[0];  // [1024,2048]
  const float* GW   = (const float*)d_in[1];  // [64,2048]
  const float* BIAS = (const float*)d_in[2];  // [64]
  const float* W13  = (const float*)d_in[3];  // [64,2816,2048]
  const float* W2   = (const float*)d_in[4];  // [64,2048,1408]
  const float* SW13 = (const float*)d_in[5];  // [5632,2048]
  const float* SW2  = (const float*)d_in[6];  // [2048,2816]
  float* Out = (float*)d_out;                 // [1024,2048]

  char* ws = (char*)d_ws;
  int*   topk_ids = (int*)(ws);                    // 6144 ints
  float* topk_w   = (float*)(ws + 24576);          // 6144 floats
  int*   offsets  = (int*)(ws + 49152);            // 65 ints (pad to 512)
  int*   tok_list = (int*)(ws + 49664);            // 6144 ints
  float* pair_w   = (float*)(ws + 74240);          // 6144 floats
  bf16*  h        = (bf16*)(ws + 98816);           // [6144,1408] bf16
  bf16*  hs       = (bf16*)(ws + 98816 + 17301504);// [1024,2816] bf16

  router_topk_kernel<<<dim3(T_TOK), 256, 0, stream>>>(X, GW, BIAS, topk_ids, topk_w);
  scatter_kernel<<<dim3(1), 1024, 0, stream>>>(topk_ids, topk_w, offsets, tok_list, pair_w);

  // routed gemm1: grid (mtiles<=8, I/64=22, E=64); dead tiles exit fast
  gemm1_kernel<128, 64, 64><<<dim3(8, I_RT / 64, NEXP), 256, 0, stream>>>(
      X, W13, h, tok_list, offsets, 0, I_RT);
  // shared gemm1: (8, 2816/64=44, 1)
  gemm1_kernel<128, 64, 64><<<dim3(8, I_SH / 64, 1), 256, 0, stream>>>(
      X, SW13, hs, nullptr, nullptr, T_TOK, I_SH);
  // shared gemm2 (plain store — initializes every element of Out)
  gemm2_kernel<128, 128, 64, false><<<dim3(8, D_HID / 128, 1), 256, 0, stream>>>(
      hs, SW2, Out, nullptr, nullptr, nullptr, T_TOK, I_SH);
  // routed gemm2 (atomic accumulate, scaled by RSF * pair weight)
  gemm2_kernel<128, 128, 64, true><<<dim3(8, D_HID / 128, NEXP), 256, 0, stream>>>(
      h, W2, Out, tok_list, offsets, pair_w, 0, I_RT);
}